// Round 7
// baseline (63258.276 us; speedup 1.0000x reference)
//
#include <hip/hip_runtime.h>
#include <math.h>

// Problem constants
#define B 256
#define Hh 512
#define S 200
#define T 200
#define VOC 512
#define G3 1536
#define PAD 36

// fp64 helpers: inner-product math in double, tensor boundaries quantized fp32.
struct d4 { double x, y, z, w; };
__device__ __forceinline__ d4 tod4(const float4 a) {
    d4 r; r.x = a.x; r.y = a.y; r.z = a.z; r.w = a.w; return r;
}
__device__ __forceinline__ double dotd(const d4& a, const d4& b) {
    return a.x * b.x + a.y * b.y + a.z * b.z + a.w * b.w;
}
__device__ __forceinline__ double sigd(double x) { return 1.0 / (1.0 + exp(-x)); }

// ---------------------------------------------------------------------------
// Table-precompute GEMM (round-2 proven, runs twice at startup only).
// ---------------------------------------------------------------------------
__global__ __launch_bounds__(256) void gemm_at(
    const float* __restrict__ A,
    const float* __restrict__ W, int ldw, int woff,
    const float* __restrict__ bias,
    float* __restrict__ C, int ldc)
{
    __shared__ float As[32][PAD];
    __shared__ float Ws[32][PAD];
    const int tid = threadIdx.x;
    const int tx = tid & 15, ty = tid >> 4;
    const int j0 = blockIdx.x * 32, m0 = blockIdx.y * 32;
    const int lr = tid >> 3, lc = (tid & 7) * 4;

    double acc00 = 0.0, acc01 = 0.0, acc10 = 0.0, acc11 = 0.0;

    for (int k0 = 0; k0 < 512; k0 += 32) {
        float4 av = *(const float4*)(A + (size_t)(m0 + lr) * 512 + k0 + lc);
        float4 wv = *(const float4*)(W + (size_t)(j0 + lr) * ldw + woff + k0 + lc);
        __syncthreads();
        *(float4*)&As[lr][lc] = av;
        *(float4*)&Ws[lr][lc] = wv;
        __syncthreads();
#pragma unroll
        for (int kk = 0; kk < 32; kk += 4) {
            d4 a0 = tod4(*(const float4*)&As[ty][kk]);
            d4 a1 = tod4(*(const float4*)&As[ty + 16][kk]);
            d4 b0 = tod4(*(const float4*)&Ws[tx][kk]);
            d4 b1 = tod4(*(const float4*)&Ws[tx + 16][kk]);
            acc00 += dotd(a0, b0);
            acc01 += dotd(a0, b1);
            acc10 += dotd(a1, b0);
            acc11 += dotd(a1, b1);
        }
    }
    const int ms[2] = { m0 + ty, m0 + ty + 16 };
    const int js[2] = { j0 + tx, j0 + tx + 16 };
    double accs[2][2] = { { acc00, acc01 }, { acc10, acc11 } };
#pragma unroll
    for (int mi = 0; mi < 2; ++mi)
#pragma unroll
        for (int ji = 0; ji < 2; ++ji) {
            int m = ms[mi], j = js[ji];
            C[(size_t)m * ldc + j] = (float)(accs[mi][ji] + (double)bias[j]);
        }
}

// ---------------------------------------------------------------------------
// Encoder GRU step, no-LDS (operands from L1/L2), 512 thr, grid (32, 8).
// Thread: j = bx*16 + (tid&15), b = by*32 + (tid>>4). Early-out per tile.
// ---------------------------------------------------------------------------
__global__ __launch_bounds__(512) void enc_step(
    const float* __restrict__ h_in, float* __restrict__ h_out,
    const float* __restrict__ gi_tab, const int* __restrict__ iseq,
    const int* __restrict__ ilen, const float* __restrict__ Whh,
    const float* __restrict__ bhh, int s, float* __restrict__ enc_out)
{
    const int tid = threadIdx.x;
    const int j = blockIdx.x * 16 + (tid & 15);
    const int b = blockIdx.y * 32 + (tid >> 4);

    int ml = 0;
    for (int i = 0; i < 32; ++i) ml = max(ml, ilen[blockIdx.y * 32 + i]);
    if (s >= ml) {   // whole tile past length: copy + zero, skip GEMM
        h_out[(size_t)b * 512 + j] = h_in[(size_t)b * 512 + j];
        enc_out[((size_t)s * B + b) * 512 + j] = 0.f;
        return;
    }

    const float* hb = h_in + (size_t)b * 512;
    const float* wr = Whh + (size_t)j * 512;
    const float* wz = Whh + (size_t)(512 + j) * 512;
    const float* wn = Whh + (size_t)(1024 + j) * 512;
    double ar = 0.0, az = 0.0, an = 0.0;
#pragma unroll 2
    for (int k = 0; k < 512; k += 4) {
        d4 hv = tod4(*(const float4*)(hb + k));
        ar += dotd(hv, tod4(*(const float4*)(wr + k)));
        az += dotd(hv, tod4(*(const float4*)(wz + k)));
        an += dotd(hv, tod4(*(const float4*)(wn + k)));
    }

    float hold = h_in[(size_t)b * 512 + j];
    float hnew = hold;
    if (s < ilen[b]) {
        int tok = iseq[s * B + b];
        const float* gi = gi_tab + (size_t)tok * G3;
        double r = sigd((double)gi[j] + ar + (double)bhh[j]);
        double z = sigd((double)gi[512 + j] + az + (double)bhh[512 + j]);
        double n = tanh((double)gi[1024 + j] + r * (an + (double)bhh[1024 + j]));
        hnew = (float)((1.0 - z) * n + z * (double)hold);
        enc_out[((size_t)s * B + b) * 512 + j] = hnew;
    } else {
        enc_out[((size_t)s * B + b) * 512 + j] = 0.f;
    }
    h_out[(size_t)b * 512 + j] = hnew;
}

// ---------------------------------------------------------------------------
// Decoder mega-kernel, 512 blocks x 256 thr:
//  blocks 0..255   (t<T):  b = bid. Phase A: ah = relu(att_W@h[b]+b) (LDS).
//                          Phase B: flash attention over enc_out (truncated +
//                          analytic zero tail). Phase C: x = tanh(mlp_tab[tok]
//                          + ctx@mlpW2.T) -> xbuf.
//  blocks 256..511 (t>=1): sb = bid-256. logits row = out_W@h[sb]+out_b (LDS,
//                          h = state after GRU step t-1), then softmax/argmax/
//                          nll in-block. Logits never touch global memory.
// ---------------------------------------------------------------------------
__global__ __launch_bounds__(256) void attn_ls(
    const float* __restrict__ enc_out, const float* __restrict__ h,
    const float* __restrict__ att_W, const float* __restrict__ att_b,
    const float* __restrict__ out_W, const float* __restrict__ out_b,
    const float* __restrict__ mlp_W, const float* __restrict__ mlp_tab,
    const int* __restrict__ input_len, const int* __restrict__ target_seq,
    int t, float* __restrict__ xbuf, float* __restrict__ nll,
    float* __restrict__ inference)
{
    __shared__ float hl[512];
    __shared__ float rowbuf[512];     // ah (attn half) or logits row (sm half)
    __shared__ float scx[4][512];
    __shared__ double sml[8];
    __shared__ float ctxl[512];
    __shared__ float red_f[256];
    __shared__ double red_d[256];
    __shared__ int red_i[256];

    const int bid = blockIdx.x, tid = threadIdx.x;
    const int lane = tid & 63, wave = tid >> 6;
    const int q = tid & 3, rbase = tid >> 2;

    if (bid < B) {
        if (t >= T) return;
        const int b = bid;
        // stage h[b] into LDS
        if (tid < 128) ((float4*)hl)[tid] = ((const float4*)(h + (size_t)b * 512))[tid];
        __syncthreads();
        // Phase A: ah = relu(att_W @ h + att_b), quad-per-row fp64 dot
        for (int pass = 0; pass < 8; ++pass) {
            const int jr = pass * 64 + rbase;
            const float* wr = att_W + (size_t)jr * 512;
            double a = 0.0;
            for (int k = q * 4; k < 512; k += 16)
                a += dotd(tod4(*(const float4*)(wr + k)),
                          tod4(*(const float4*)&hl[k]));
            a += __shfl_xor(a, 1, 64);
            a += __shfl_xor(a, 2, 64);
            if (q == 0) {
                double v = a + (double)att_b[jr];
                rowbuf[jr] = (float)(v > 0.0 ? v : 0.0);   // fp32 boundary
            }
        }
        __syncthreads();

        // Phase B: flash attention (round-6 proven)
        const int len = input_len[b];
        d4 aa1 = tod4(*(const float4*)&rowbuf[lane * 4]);
        d4 aa2 = tod4(*(const float4*)&rowbuf[256 + lane * 4]);
        double m = -INFINITY, l = 0.0;
        d4 c1 = {0,0,0,0}, c2 = {0,0,0,0};
        for (int s = wave; s < len; s += 4) {
            const float* row = enc_out + ((size_t)s * B + b) * 512;
            d4 e1 = tod4(*(const float4*)(row + lane * 4));
            d4 e2 = tod4(*(const float4*)(row + 256 + lane * 4));
            double p = dotd(e1, aa1) + dotd(e2, aa2);
#pragma unroll
            for (int off = 32; off >= 1; off >>= 1) p += __shfl_xor(p, off, 64);
            double mn = fmax(m, p);
            double sc = (m == mn) ? 1.0 : exp(m - mn);
            double w = exp(p - mn);
            l = l * sc + w;
            c1.x = c1.x * sc + w * e1.x; c1.y = c1.y * sc + w * e1.y;
            c1.z = c1.z * sc + w * e1.z; c1.w = c1.w * sc + w * e1.w;
            c2.x = c2.x * sc + w * e2.x; c2.y = c2.y * sc + w * e2.y;
            c2.z = c2.z * sc + w * e2.z; c2.w = c2.w * sc + w * e2.w;
            m = mn;
        }
        if (lane == 0) { sml[wave] = m; sml[4 + wave] = l; }
        *(float4*)&scx[wave][lane * 4] =
            make_float4((float)c1.x, (float)c1.y, (float)c1.z, (float)c1.w);
        *(float4*)&scx[wave][256 + lane * 4] =
            make_float4((float)c2.x, (float)c2.y, (float)c2.z, (float)c2.w);
        __syncthreads();
        double M = fmax(fmax(sml[0], sml[1]), fmax(sml[2], sml[3]));
        if (len < S) M = fmax(M, 0.0);   // zero rows participate in softmax
        double w0 = exp(sml[0] - M), w1x = exp(sml[1] - M);
        double w2x = exp(sml[2] - M), w3 = exp(sml[3] - M);
        double L = sml[4] * w0 + sml[5] * w1x + sml[6] * w2x + sml[7] * w3
                 + (double)(S - len) * exp(0.0 - M);   // analytic zero tail
        for (int jj = tid; jj < 512; jj += 256) {
            double v = (double)scx[0][jj] * w0 + (double)scx[1][jj] * w1x
                     + (double)scx[2][jj] * w2x + (double)scx[3][jj] * w3;
            ctxl[jj] = (float)(v / L);   // fp32 boundary (as ref)
        }
        __syncthreads();

        // Phase C: x = tanh(mlp_tab[tok] + ctx @ mlpW2.T), quad-per-row
        const int tok = (t == 0) ? 1 : target_seq[(t - 1) * B + b];
#pragma unroll
        for (int pass = 0; pass < 8; ++pass) {
            const int jr = pass * 64 + rbase;
            const float* wr = mlp_W + (size_t)jr * 1024 + 512;
            double a = 0.0;
            for (int k = q * 4; k < 512; k += 16) {
                a += dotd(tod4(*(const float4*)&ctxl[k]),
                          tod4(*(const float4*)(wr + k)));
            }
            a += __shfl_xor(a, 1, 64);
            a += __shfl_xor(a, 2, 64);
            if (q == 0)
                xbuf[(size_t)b * 512 + jr] =
                    (float)tanh((double)mlp_tab[(size_t)tok * 512 + jr] + a);
        }
    } else {
        if (t < 1) return;
        const int sb = bid - B;
        // stage h[sb] (this is hn of step t-1)
        if (tid < 128) ((float4*)hl)[tid] = ((const float4*)(h + (size_t)sb * 512))[tid];
        __syncthreads();
        // logits row = out_W @ h + out_b -> LDS (fp32 boundary)
        for (int pass = 0; pass < 8; ++pass) {
            const int jr = pass * 64 + rbase;
            const float* wr = out_W + (size_t)jr * 512;
            double a = 0.0;
            for (int k = q * 4; k < 512; k += 16)
                a += dotd(tod4(*(const float4*)(wr + k)),
                          tod4(*(const float4*)&hl[k]));
            a += __shfl_xor(a, 1, 64);
            a += __shfl_xor(a, 2, 64);
            if (q == 0) rowbuf[jr] = (float)(a + (double)out_b[jr]);
        }
        __syncthreads();
        // softmax / argmax / nll (round-6 proven block logic)
        const float l0 = rowbuf[tid], l1 = rowbuf[256 + tid];
        red_f[tid] = fmaxf(l0, l1);
        __syncthreads();
        for (int off = 128; off > 0; off >>= 1) {
            if (tid < off) red_f[tid] = fmaxf(red_f[tid], red_f[tid + off]);
            __syncthreads();
        }
        const double mx = (double)red_f[0];
        __syncthreads();
        const double e0 = exp((double)l0 - mx), e1 = exp((double)l1 - mx);
        red_d[tid] = e0 + e1;
        __syncthreads();
        for (int off = 128; off > 0; off >>= 1) {
            if (tid < off) red_d[tid] += red_d[tid + off];
            __syncthreads();
        }
        const double Z = red_d[0];
        __syncthreads();
        const float p0 = (float)(e0 / Z), p1 = (float)(e1 / Z);
        float v; int idx;
        if (p0 >= p1) { v = p0; idx = tid; } else { v = p1; idx = 256 + tid; }
        red_f[tid] = v; red_i[tid] = idx;
        __syncthreads();
        for (int off = 128; off > 0; off >>= 1) {
            if (tid < off) {
                float ov = red_f[tid + off]; int oi = red_i[tid + off];
                if (ov > red_f[tid] || (ov == red_f[tid] && oi < red_i[tid])) {
                    red_f[tid] = ov; red_i[tid] = oi;
                }
            }
            __syncthreads();
        }
        if (tid == 0) {
            int tg = target_seq[(t - 1) * B + sb];
            float pt = (float)(exp((double)rowbuf[tg] - mx) / Z);
            pt = fmaxf(pt, 1e-10f);
            nll[(t - 1) * B + sb] = (float)(-log((double)pt));
            inference[(t - 1) * B + sb] = (float)red_i[0];
        }
    }
}

// ---------------------------------------------------------------------------
// Decoder GRU, no-LDS, 2-batch register tiling. Grid (32, 8), 256 thr.
// Thread: j = bx*16 + (tid&15); b1 = by*32 + (tid>>4), b2 = b1+16.
// 12 fp64 accumulators; 48 FMA per 10 float4 loads.
// ---------------------------------------------------------------------------
__global__ __launch_bounds__(256) void dec_gru(
    const float* __restrict__ x, const float* __restrict__ h_in,
    const float* __restrict__ Wih, const float* __restrict__ Whh,
    const float* __restrict__ bih, const float* __restrict__ bhh,
    float* __restrict__ h_out)
{
    const int tid = threadIdx.x;
    const int j = blockIdx.x * 16 + (tid & 15);
    const int b1 = blockIdx.y * 32 + (tid >> 4), b2 = b1 + 16;

    const float* x1 = x + (size_t)b1 * 512;
    const float* x2 = x + (size_t)b2 * 512;
    const float* h1p = h_in + (size_t)b1 * 512;
    const float* h2p = h_in + (size_t)b2 * 512;
    const float* wir = Wih + (size_t)j * 512;
    const float* wiz = Wih + (size_t)(512 + j) * 512;
    const float* win = Wih + (size_t)(1024 + j) * 512;
    const float* whr = Whh + (size_t)j * 512;
    const float* whz = Whh + (size_t)(512 + j) * 512;
    const float* whn = Whh + (size_t)(1024 + j) * 512;

    double air1 = 0, aiz1 = 0, ain1 = 0, ahr1 = 0, ahz1 = 0, ahn1 = 0;
    double air2 = 0, aiz2 = 0, ain2 = 0, ahr2 = 0, ahz2 = 0, ahn2 = 0;

#pragma unroll 2
    for (int k = 0; k < 512; k += 4) {
        d4 vir = tod4(*(const float4*)(wir + k));
        d4 viz = tod4(*(const float4*)(wiz + k));
        d4 vin = tod4(*(const float4*)(win + k));
        d4 vhr = tod4(*(const float4*)(whr + k));
        d4 vhz = tod4(*(const float4*)(whz + k));
        d4 vhn = tod4(*(const float4*)(whn + k));
        d4 xv1 = tod4(*(const float4*)(x1 + k));
        d4 hv1 = tod4(*(const float4*)(h1p + k));
        d4 xv2 = tod4(*(const float4*)(x2 + k));
        d4 hv2 = tod4(*(const float4*)(h2p + k));
        air1 += dotd(xv1, vir); aiz1 += dotd(xv1, viz); ain1 += dotd(xv1, vin);
        ahr1 += dotd(hv1, vhr); ahz1 += dotd(hv1, vhz); ahn1 += dotd(hv1, vhn);
        air2 += dotd(xv2, vir); aiz2 += dotd(xv2, viz); ain2 += dotd(xv2, vin);
        ahr2 += dotd(hv2, vhr); ahz2 += dotd(hv2, vhz); ahn2 += dotd(hv2, vhn);
    }

    const double bir = (double)bih[j], biz = (double)bih[512 + j], bin = (double)bih[1024 + j];
    const double bhr = (double)bhh[j], bhz = (double)bhh[512 + j], bhn = (double)bhh[1024 + j];
    {
        double r = sigd(air1 + bir + ahr1 + bhr);
        double z = sigd(aiz1 + biz + ahz1 + bhz);
        double n = tanh(ain1 + bin + r * (ahn1 + bhn));
        float hold = h_in[(size_t)b1 * 512 + j];
        h_out[(size_t)b1 * 512 + j] = (float)((1.0 - z) * n + z * (double)hold);
    }
    {
        double r = sigd(air2 + bir + ahr2 + bhr);
        double z = sigd(aiz2 + biz + ahz2 + bhz);
        double n = tanh(ain2 + bin + r * (ahn2 + bhn));
        float hold = h_in[(size_t)b2 * 512 + j];
        h_out[(size_t)b2 * 512 + j] = (float)((1.0 - z) * n + z * (double)hold);
    }
}

// ---------------------------------------------------------------------------
// Final reduction (round-2 proven).
// ---------------------------------------------------------------------------
__global__ __launch_bounds__(256) void finalize_k(
    const float* __restrict__ nll, const float* __restrict__ inference,
    const int* __restrict__ target, float* __restrict__ out3)
{
    const int tid = threadIdx.x;
    int wrong = 0;
    double match = 0.0;
    const int b = tid;
    for (int t = 0; t < T; ++t) {
        float inf = inference[t * B + b];
        float tg = (float)target[t * B + b];
        bool ok = (inf == tg);
        match += ok ? 1.0 : 0.0;
        wrong |= !ok;
    }
    double lsum = 0.0;
    for (int i = tid; i < T * B; i += 256) lsum += (double)nll[i];

    __shared__ double sl[256], sm_[256], sa[256];
    sl[tid] = lsum; sm_[tid] = match; sa[tid] = wrong ? 0.0 : 1.0;
    __syncthreads();
    for (int off = 128; off > 0; off >>= 1) {
        if (tid < off) {
            sl[tid] += sl[tid + off];
            sm_[tid] += sm_[tid + off];
            sa[tid] += sa[tid + off];
        }
        __syncthreads();
    }
    if (tid == 0) {
        out3[0] = (float)(sl[0] / (double)(T * B));
        out3[1] = (float)(sa[0] / (double)B);
        out3[2] = (float)(sm_[0] / (double)(T * B));
    }
}

// ---------------------------------------------------------------------------
extern "C" void kernel_launch(void* const* d_in, const int* in_sizes, int n_in,
                              void* d_out, int out_size, void* d_ws, size_t ws_size,
                              hipStream_t stream)
{
    const int*   input_seq  = (const int*)d_in[0];
    const int*   input_len  = (const int*)d_in[1];
    const int*   target_seq = (const int*)d_in[2];
    const float* enc_embed  = (const float*)d_in[3];
    const float* enc_Wih    = (const float*)d_in[4];
    const float* enc_Whh    = (const float*)d_in[5];
    const float* enc_bih    = (const float*)d_in[6];
    const float* enc_bhh    = (const float*)d_in[7];
    const float* att_W      = (const float*)d_in[8];
    const float* att_b      = (const float*)d_in[9];
    const float* dec_embed  = (const float*)d_in[10];
    const float* dec_Wih    = (const float*)d_in[11];
    const float* dec_Whh    = (const float*)d_in[12];
    const float* dec_bih    = (const float*)d_in[13];
    const float* dec_bhh    = (const float*)d_in[14];
    const float* mlp_W      = (const float*)d_in[15];
    const float* mlp_b      = (const float*)d_in[16];
    const float* out_W      = (const float*)d_in[17];
    const float* out_b      = (const float*)d_in[18];

    float* out = (float*)d_out;   // [inference (T*B) | loss | acc | all_acc]

    float* gi_tab  = (float*)d_ws;                   // (V, 3H)
    float* mlp_tab = gi_tab + (size_t)VOC * G3;      // (V, H)
    float* h0      = mlp_tab + (size_t)VOC * Hh;     // (B, H)
    float* h1      = h0 + (size_t)B * Hh;
    float* xb      = h1 + (size_t)B * Hh;
    float* nllb    = xb + (size_t)B * Hh;            // (T, B)
    float* enc_out = nllb + (size_t)T * B;           // (S, B, H) ~105 MB

    hipMemsetAsync(h0, 0, (size_t)B * Hh * sizeof(float), stream);

    // Precompute tables:
    gemm_at<<<dim3(48, 16), 256, 0, stream>>>(
        enc_embed, enc_Wih, 512, 0, enc_bih, gi_tab, G3);
    gemm_at<<<dim3(16, 16), 256, 0, stream>>>(
        dec_embed, mlp_W, 1024, 0, mlp_b, mlp_tab, Hh);

    // Encoder scan (final h lands in h0: s=199 odd writes h0)
    for (int s = 0; s < S; ++s) {
        const float* hc = (s & 1) ? h1 : h0;
        float* hx = (s & 1) ? h0 : h1;
        enc_step<<<dim3(32, 8), 512, 0, stream>>>(
            hc, hx, gi_tab, input_seq, input_len, enc_Whh, enc_bhh, s, enc_out);
    }

    // Decoder scan: t = 0..T. attn_ls does attention+x (blocks 0..255, t<T)
    // and logits+softmax of step t-1 (blocks 256..511, t>=1) concurrently.
    for (int t = 0; t <= T; ++t) {
        const float* hc = (t & 1) ? h1 : h0;
        float* hx = (t & 1) ? h0 : h1;
        attn_ls<<<dim3(2 * B), 256, 0, stream>>>(
            enc_out, hc, att_W, att_b, out_W, out_b, mlp_W, mlp_tab,
            input_len, target_seq, t, xb, nllb, out);
        if (t < T) {
            dec_gru<<<dim3(32, 8), 256, 0, stream>>>(
                xb, hc, dec_Wih, dec_Whh, dec_bih, dec_bhh, hx);
        }
    }

    finalize_k<<<dim3(1), 256, 0, stream>>>(nllb, out, target_seq, out + (size_t)T * B);
}

// Round 8
// 39117.520 us; speedup vs baseline: 1.6171x; 1.6171x over previous
//
#include <hip/hip_runtime.h>
#include <math.h>

// Problem constants
#define B 256
#define Hh 512
#define S 200
#define T 200
#define VOC 512
#define G3 1536
#define PAD 36
#define DPAD 36   // dec_gru LDS row stride (floats), 16B-aligned rows

// fp64 helpers: inner-product math in double, tensor boundaries quantized fp32.
struct d4 { double x, y, z, w; };
__device__ __forceinline__ d4 tod4(const float4 a) {
    d4 r; r.x = a.x; r.y = a.y; r.z = a.z; r.w = a.w; return r;
}
__device__ __forceinline__ double dotd(const d4& a, const d4& b) {
    return a.x * b.x + a.y * b.y + a.z * b.z + a.w * b.w;
}
__device__ __forceinline__ double sigd(double x) { return 1.0 / (1.0 + exp(-x)); }

// ---------------------------------------------------------------------------
// Table-precompute GEMM (round-2 proven, startup only).
// ---------------------------------------------------------------------------
__global__ __launch_bounds__(256) void gemm_at(
    const float* __restrict__ A,
    const float* __restrict__ W, int ldw, int woff,
    const float* __restrict__ bias,
    float* __restrict__ C, int ldc)
{
    __shared__ float As[32][PAD];
    __shared__ float Ws[32][PAD];
    const int tid = threadIdx.x;
    const int tx = tid & 15, ty = tid >> 4;
    const int j0 = blockIdx.x * 32, m0 = blockIdx.y * 32;
    const int lr = tid >> 3, lc = (tid & 7) * 4;

    double acc00 = 0.0, acc01 = 0.0, acc10 = 0.0, acc11 = 0.0;

    for (int k0 = 0; k0 < 512; k0 += 32) {
        float4 av = *(const float4*)(A + (size_t)(m0 + lr) * 512 + k0 + lc);
        float4 wv = *(const float4*)(W + (size_t)(j0 + lr) * ldw + woff + k0 + lc);
        __syncthreads();
        *(float4*)&As[lr][lc] = av;
        *(float4*)&Ws[lr][lc] = wv;
        __syncthreads();
#pragma unroll
        for (int kk = 0; kk < 32; kk += 4) {
            d4 a0 = tod4(*(const float4*)&As[ty][kk]);
            d4 a1 = tod4(*(const float4*)&As[ty + 16][kk]);
            d4 b0 = tod4(*(const float4*)&Ws[tx][kk]);
            d4 b1 = tod4(*(const float4*)&Ws[tx + 16][kk]);
            acc00 += dotd(a0, b0);
            acc01 += dotd(a0, b1);
            acc10 += dotd(a1, b0);
            acc11 += dotd(a1, b1);
        }
    }
    const int ms[2] = { m0 + ty, m0 + ty + 16 };
    const int js[2] = { j0 + tx, j0 + tx + 16 };
    double accs[2][2] = { { acc00, acc01 }, { acc10, acc11 } };
#pragma unroll
    for (int mi = 0; mi < 2; ++mi)
#pragma unroll
        for (int ji = 0; ji < 2; ++ji) {
            int m = ms[mi], j = js[ji];
            C[(size_t)m * ldc + j] = (float)(accs[mi][ji] + (double)bias[j]);
        }
}

// ---------------------------------------------------------------------------
// Encoder GRU step — round-6 version verbatim (LDS-staged, 512 thr, 2 w/SIMD).
// ---------------------------------------------------------------------------
__global__ __launch_bounds__(512) void enc_step(
    const float* __restrict__ h_in, float* __restrict__ h_out,
    const float* __restrict__ gi_tab, const int* __restrict__ iseq,
    const int* __restrict__ ilen, const float* __restrict__ Whh,
    const float* __restrict__ bhh, int s, float* __restrict__ enc_out)
{
    __shared__ float Hs[32][68];
    __shared__ float Ws[48][68];
    const int tid = threadIdx.x;
    const int j_l = tid & 15, b_l = tid >> 4;
    const int j0 = blockIdx.x * 16, b0 = blockIdx.y * 32;
    const int j = j0 + j_l, b = b0 + b_l;

    int ml = 0;
    for (int i = 0; i < 32; ++i) ml = max(ml, ilen[b0 + i]);
    if (s >= ml) {
        h_out[(size_t)b * 512 + j] = h_in[(size_t)b * 512 + j];
        enc_out[((size_t)s * B + b) * 512 + j] = 0.f;
        return;
    }

    double ar = 0.0, az = 0.0, an = 0.0;
    for (int kt = 0; kt < 512; kt += 64) {
        __syncthreads();
        {
            int row = tid >> 4, c4 = (tid & 15) * 4;
            *(float4*)&Hs[row][c4] =
                *(const float4*)(h_in + (size_t)(b0 + row) * 512 + kt + c4);
            for (int idx = tid; idx < 768; idx += 512) {
                int r = idx >> 4, cc = (idx & 15) * 4;
                int g = r >> 4, jj = r & 15;
                *(float4*)&Ws[r][cc] =
                    *(const float4*)(Whh + (size_t)(g * 512 + j0 + jj) * 512 + kt + cc);
            }
        }
        __syncthreads();
#pragma unroll
        for (int kk = 0; kk < 64; kk += 4) {
            d4 hv = tod4(*(const float4*)&Hs[b_l][kk]);
            ar += dotd(hv, tod4(*(const float4*)&Ws[j_l][kk]));
            az += dotd(hv, tod4(*(const float4*)&Ws[16 + j_l][kk]));
            an += dotd(hv, tod4(*(const float4*)&Ws[32 + j_l][kk]));
        }
    }

    float hold = h_in[(size_t)b * 512 + j];
    float hnew = hold;
    if (s < ilen[b]) {
        int tok = iseq[s * B + b];
        const float* gi = gi_tab + (size_t)tok * G3;
        double r = sigd((double)gi[j] + ar + (double)bhh[j]);
        double z = sigd((double)gi[512 + j] + az + (double)bhh[512 + j]);
        double n = tanh((double)gi[1024 + j] + r * (an + (double)bhh[1024 + j]));
        hnew = (float)((1.0 - z) * n + z * (double)hold);
        enc_out[((size_t)s * B + b) * 512 + j] = hnew;
    } else {
        enc_out[((size_t)s * B + b) * 512 + j] = 0.f;
    }
    h_out[(size_t)b * 512 + j] = hnew;
}

// ---------------------------------------------------------------------------
// Decoder fused attention/logits kernel — round-7 version verbatim (passed).
//  blocks 0..255   (t<T):  ah = relu(att_W@h+b) -> flash attention -> x.
//  blocks 256..511 (t>=1): logits row in LDS -> softmax/argmax/nll.
// ---------------------------------------------------------------------------
__global__ __launch_bounds__(256) void attn_ls(
    const float* __restrict__ enc_out, const float* __restrict__ h,
    const float* __restrict__ att_W, const float* __restrict__ att_b,
    const float* __restrict__ out_W, const float* __restrict__ out_b,
    const float* __restrict__ mlp_W, const float* __restrict__ mlp_tab,
    const int* __restrict__ input_len, const int* __restrict__ target_seq,
    int t, float* __restrict__ xbuf, float* __restrict__ nll,
    float* __restrict__ inference)
{
    __shared__ float hl[512];
    __shared__ float rowbuf[512];
    __shared__ float scx[4][512];
    __shared__ double sml[8];
    __shared__ float ctxl[512];
    __shared__ float red_f[256];
    __shared__ double red_d[256];
    __shared__ int red_i[256];

    const int bid = blockIdx.x, tid = threadIdx.x;
    const int lane = tid & 63, wave = tid >> 6;
    const int q = tid & 3, rbase = tid >> 2;

    if (bid < B) {
        if (t >= T) return;
        const int b = bid;
        if (tid < 128) ((float4*)hl)[tid] = ((const float4*)(h + (size_t)b * 512))[tid];
        __syncthreads();
        for (int pass = 0; pass < 8; ++pass) {
            const int jr = pass * 64 + rbase;
            const float* wr = att_W + (size_t)jr * 512;
            double a = 0.0;
            for (int k = q * 4; k < 512; k += 16)
                a += dotd(tod4(*(const float4*)(wr + k)),
                          tod4(*(const float4*)&hl[k]));
            a += __shfl_xor(a, 1, 64);
            a += __shfl_xor(a, 2, 64);
            if (q == 0) {
                double v = a + (double)att_b[jr];
                rowbuf[jr] = (float)(v > 0.0 ? v : 0.0);
            }
        }
        __syncthreads();

        const int len = input_len[b];
        d4 aa1 = tod4(*(const float4*)&rowbuf[lane * 4]);
        d4 aa2 = tod4(*(const float4*)&rowbuf[256 + lane * 4]);
        double m = -INFINITY, l = 0.0;
        d4 c1 = {0,0,0,0}, c2 = {0,0,0,0};
        for (int s = wave; s < len; s += 4) {
            const float* row = enc_out + ((size_t)s * B + b) * 512;
            d4 e1 = tod4(*(const float4*)(row + lane * 4));
            d4 e2 = tod4(*(const float4*)(row + 256 + lane * 4));
            double p = dotd(e1, aa1) + dotd(e2, aa2);
#pragma unroll
            for (int off = 32; off >= 1; off >>= 1) p += __shfl_xor(p, off, 64);
            double mn = fmax(m, p);
            double sc = (m == mn) ? 1.0 : exp(m - mn);
            double w = exp(p - mn);
            l = l * sc + w;
            c1.x = c1.x * sc + w * e1.x; c1.y = c1.y * sc + w * e1.y;
            c1.z = c1.z * sc + w * e1.z; c1.w = c1.w * sc + w * e1.w;
            c2.x = c2.x * sc + w * e2.x; c2.y = c2.y * sc + w * e2.y;
            c2.z = c2.z * sc + w * e2.z; c2.w = c2.w * sc + w * e2.w;
            m = mn;
        }
        if (lane == 0) { sml[wave] = m; sml[4 + wave] = l; }
        *(float4*)&scx[wave][lane * 4] =
            make_float4((float)c1.x, (float)c1.y, (float)c1.z, (float)c1.w);
        *(float4*)&scx[wave][256 + lane * 4] =
            make_float4((float)c2.x, (float)c2.y, (float)c2.z, (float)c2.w);
        __syncthreads();
        double M = fmax(fmax(sml[0], sml[1]), fmax(sml[2], sml[3]));
        if (len < S) M = fmax(M, 0.0);
        double w0 = exp(sml[0] - M), w1x = exp(sml[1] - M);
        double w2x = exp(sml[2] - M), w3 = exp(sml[3] - M);
        double L = sml[4] * w0 + sml[5] * w1x + sml[6] * w2x + sml[7] * w3
                 + (double)(S - len) * exp(0.0 - M);
        for (int jj = tid; jj < 512; jj += 256) {
            double v = (double)scx[0][jj] * w0 + (double)scx[1][jj] * w1x
                     + (double)scx[2][jj] * w2x + (double)scx[3][jj] * w3;
            ctxl[jj] = (float)(v / L);
        }
        __syncthreads();

        const int tok = (t == 0) ? 1 : target_seq[(t - 1) * B + b];
#pragma unroll
        for (int pass = 0; pass < 8; ++pass) {
            const int jr = pass * 64 + rbase;
            const float* wr = mlp_W + (size_t)jr * 1024 + 512;
            double a = 0.0;
            for (int k = q * 4; k < 512; k += 16) {
                a += dotd(tod4(*(const float4*)&ctxl[k]),
                          tod4(*(const float4*)(wr + k)));
            }
            a += __shfl_xor(a, 1, 64);
            a += __shfl_xor(a, 2, 64);
            if (q == 0)
                xbuf[(size_t)b * 512 + jr] =
                    (float)tanh((double)mlp_tab[(size_t)tok * 512 + jr] + a);
        }
    } else {
        if (t < 1) return;
        const int sb = bid - B;
        if (tid < 128) ((float4*)hl)[tid] = ((const float4*)(h + (size_t)sb * 512))[tid];
        __syncthreads();
        for (int pass = 0; pass < 8; ++pass) {
            const int jr = pass * 64 + rbase;
            const float* wr = out_W + (size_t)jr * 512;
            double a = 0.0;
            for (int k = q * 4; k < 512; k += 16)
                a += dotd(tod4(*(const float4*)(wr + k)),
                          tod4(*(const float4*)&hl[k]));
            a += __shfl_xor(a, 1, 64);
            a += __shfl_xor(a, 2, 64);
            if (q == 0) rowbuf[jr] = (float)(a + (double)out_b[jr]);
        }
        __syncthreads();
        const float l0 = rowbuf[tid], l1 = rowbuf[256 + tid];
        red_f[tid] = fmaxf(l0, l1);
        __syncthreads();
        for (int off = 128; off > 0; off >>= 1) {
            if (tid < off) red_f[tid] = fmaxf(red_f[tid], red_f[tid + off]);
            __syncthreads();
        }
        const double mx = (double)red_f[0];
        __syncthreads();
        const double e0 = exp((double)l0 - mx), e1 = exp((double)l1 - mx);
        red_d[tid] = e0 + e1;
        __syncthreads();
        for (int off = 128; off > 0; off >>= 1) {
            if (tid < off) red_d[tid] += red_d[tid + off];
            __syncthreads();
        }
        const double Z = red_d[0];
        __syncthreads();
        const float p0 = (float)(e0 / Z), p1 = (float)(e1 / Z);
        float v; int idx;
        if (p0 >= p1) { v = p0; idx = tid; } else { v = p1; idx = 256 + tid; }
        red_f[tid] = v; red_i[tid] = idx;
        __syncthreads();
        for (int off = 128; off > 0; off >>= 1) {
            if (tid < off) {
                float ov = red_f[tid + off]; int oi = red_i[tid + off];
                if (ov > red_f[tid] || (ov == red_f[tid] && oi < red_i[tid])) {
                    red_f[tid] = ov; red_i[tid] = oi;
                }
            }
            __syncthreads();
        }
        if (tid == 0) {
            int tg = target_seq[(t - 1) * B + sb];
            float pt = (float)(exp((double)rowbuf[tg] - mx) / Z);
            pt = fmaxf(pt, 1e-10f);
            nll[(t - 1) * B + sb] = (float)(-log((double)pt));
            inference[(t - 1) * B + sb] = (float)red_i[0];
        }
    }
}

// ---------------------------------------------------------------------------
// Decoder GRU v3: grid (32,16) = 512 blocks x 256 thr (2+/CU), tile 16j x 16b.
// Thread = (ks = tid&1, j_l = (tid>>1)&15, bp = tid>>5): computes (j, b1=bp)
// and (j, b2=bp+8), k-range split by ks (256 each), combined via shfl_xor(1).
// LDS ~36.9 KB; 10 ds_read_b128 per 48 FMAs -> VALU-bound.
// ---------------------------------------------------------------------------
__global__ __launch_bounds__(256) void dec_gru(
    const float* __restrict__ x, const float* __restrict__ h_in,
    const float* __restrict__ Wih, const float* __restrict__ Whh,
    const float* __restrict__ bih, const float* __restrict__ bhh,
    float* __restrict__ h_out)
{
    __shared__ float Xs[32 * DPAD];    // rows: b_row*2 + ks
    __shared__ float Hs[32 * DPAD];
    __shared__ float Wi[96 * DPAD];    // rows: (g*16 + jj)*2 + ks
    __shared__ float Wh[96 * DPAD];

    const int tid = threadIdx.x;
    const int ks = tid & 1;
    const int j_l = (tid >> 1) & 15;
    const int bp = tid >> 5;                  // 0..7
    const int j0 = blockIdx.x * 16, b0 = blockIdx.y * 16;
    const int j = j0 + j_l;
    const int b1 = b0 + bp, b2 = b0 + bp + 8;

    double air1=0, aiz1=0, ain1=0, ahr1=0, ahz1=0, ahn1=0;
    double air2=0, aiz2=0, ain2=0, ahr2=0, ahz2=0, ahn2=0;

    const float* xr1p; const float* xr2p; const float* hr1p; const float* hr2p;
    const float* wiRp; const float* wiZp; const float* wiNp;
    const float* whRp; const float* whZp; const float* whNp;
    xr1p = &Xs[(bp * 2 + ks) * DPAD];
    xr2p = &Xs[((bp + 8) * 2 + ks) * DPAD];
    hr1p = &Hs[(bp * 2 + ks) * DPAD];
    hr2p = &Hs[((bp + 8) * 2 + ks) * DPAD];
    wiRp = &Wi[((0 * 16 + j_l) * 2 + ks) * DPAD];
    wiZp = &Wi[((1 * 16 + j_l) * 2 + ks) * DPAD];
    wiNp = &Wi[((2 * 16 + j_l) * 2 + ks) * DPAD];
    whRp = &Wh[((0 * 16 + j_l) * 2 + ks) * DPAD];
    whZp = &Wh[((1 * 16 + j_l) * 2 + ks) * DPAD];
    whNp = &Wh[((2 * 16 + j_l) * 2 + ks) * DPAD];

    for (int kt = 0; kt < 256; kt += 32) {
        __syncthreads();
        // stage: 2048 float4 total (X 256, H 256, Wi 768, Wh 768), 8/thread
        for (int idx = tid; idx < 2048; idx += 256) {
            if (idx < 256) {
                int br = idx >> 4, c = idx & 15;
                int kss = c >> 3, f4i = c & 7;
                *(float4*)&Xs[(br * 2 + kss) * DPAD + f4i * 4] =
                    *(const float4*)(x + (size_t)(b0 + br) * 512 + kt + kss * 256 + f4i * 4);
            } else if (idx < 512) {
                int w = idx - 256;
                int br = w >> 4, c = w & 15;
                int kss = c >> 3, f4i = c & 7;
                *(float4*)&Hs[(br * 2 + kss) * DPAD + f4i * 4] =
                    *(const float4*)(h_in + (size_t)(b0 + br) * 512 + kt + kss * 256 + f4i * 4);
            } else if (idx < 1280) {
                int w = idx - 512;
                int row = w >> 4, c = w & 15;
                int kss = c >> 3, f4i = c & 7;
                int g = row >> 4, jj = row & 15;
                *(float4*)&Wi[(row * 2 + kss) * DPAD + f4i * 4] =
                    *(const float4*)(Wih + (size_t)(g * 512 + j0 + jj) * 512 + kt + kss * 256 + f4i * 4);
            } else {
                int w = idx - 1280;
                int row = w >> 4, c = w & 15;
                int kss = c >> 3, f4i = c & 7;
                int g = row >> 4, jj = row & 15;
                *(float4*)&Wh[(row * 2 + kss) * DPAD + f4i * 4] =
                    *(const float4*)(Whh + (size_t)(g * 512 + j0 + jj) * 512 + kt + kss * 256 + f4i * 4);
            }
        }
        __syncthreads();
#pragma unroll
        for (int kk = 0; kk < 32; kk += 4) {
            d4 xv1 = tod4(*(const float4*)(xr1p + kk));
            d4 xv2 = tod4(*(const float4*)(xr2p + kk));
            d4 hv1 = tod4(*(const float4*)(hr1p + kk));
            d4 hv2 = tod4(*(const float4*)(hr2p + kk));
            d4 vir = tod4(*(const float4*)(wiRp + kk));
            d4 viz = tod4(*(const float4*)(wiZp + kk));
            d4 vin = tod4(*(const float4*)(wiNp + kk));
            d4 vhr = tod4(*(const float4*)(whRp + kk));
            d4 vhz = tod4(*(const float4*)(whZp + kk));
            d4 vhn = tod4(*(const float4*)(whNp + kk));
            air1 += dotd(xv1, vir); aiz1 += dotd(xv1, viz); ain1 += dotd(xv1, vin);
            ahr1 += dotd(hv1, vhr); ahz1 += dotd(hv1, vhz); ahn1 += dotd(hv1, vhn);
            air2 += dotd(xv2, vir); aiz2 += dotd(xv2, viz); ain2 += dotd(xv2, vin);
            ahr2 += dotd(hv2, vhr); ahz2 += dotd(hv2, vhz); ahn2 += dotd(hv2, vhn);
        }
    }

    // combine ks halves (lane^1 is the partner; fp64 add is commutative)
    air1 += __shfl_xor(air1, 1, 64); aiz1 += __shfl_xor(aiz1, 1, 64);
    ain1 += __shfl_xor(ain1, 1, 64); ahr1 += __shfl_xor(ahr1, 1, 64);
    ahz1 += __shfl_xor(ahz1, 1, 64); ahn1 += __shfl_xor(ahn1, 1, 64);
    air2 += __shfl_xor(air2, 1, 64); aiz2 += __shfl_xor(aiz2, 1, 64);
    ain2 += __shfl_xor(ain2, 1, 64); ahr2 += __shfl_xor(ahr2, 1, 64);
    ahz2 += __shfl_xor(ahz2, 1, 64); ahn2 += __shfl_xor(ahn2, 1, 64);

    // ks=0 lane finalizes b1, ks=1 lane finalizes b2 (split epilogue)
    const int bb = ks ? b2 : b1;
    const double air = ks ? air2 : air1, aiz = ks ? aiz2 : aiz1, ain = ks ? ain2 : ain1;
    const double ahr = ks ? ahr2 : ahr1, ahz = ks ? ahz2 : ahz1, ahn = ks ? ahn2 : ahn1;
    double r = sigd(air + (double)bih[j] + ahr + (double)bhh[j]);
    double z = sigd(aiz + (double)bih[512 + j] + ahz + (double)bhh[512 + j]);
    double n = tanh(ain + (double)bih[1024 + j] + r * (ahn + (double)bhh[1024 + j]));
    float hold = h_in[(size_t)bb * 512 + j];
    h_out[(size_t)bb * 512 + j] = (float)((1.0 - z) * n + z * (double)hold);
}

// ---------------------------------------------------------------------------
// Final reduction (round-2 proven).
// ---------------------------------------------------------------------------
__global__ __launch_bounds__(256) void finalize_k(
    const float* __restrict__ nll, const float* __restrict__ inference,
    const int* __restrict__ target, float* __restrict__ out3)
{
    const int tid = threadIdx.x;
    int wrong = 0;
    double match = 0.0;
    const int b = tid;
    for (int t = 0; t < T; ++t) {
        float inf = inference[t * B + b];
        float tg = (float)target[t * B + b];
        bool ok = (inf == tg);
        match += ok ? 1.0 : 0.0;
        wrong |= !ok;
    }
    double lsum = 0.0;
    for (int i = tid; i < T * B; i += 256) lsum += (double)nll[i];

    __shared__ double sl[256], sm_[256], sa[256];
    sl[tid] = lsum; sm_[tid] = match; sa[tid] = wrong ? 0.0 : 1.0;
    __syncthreads();
    for (int off = 128; off > 0; off >>= 1) {
        if (tid < off) {
            sl[tid] += sl[tid + off];
            sm_[tid] += sm_[tid + off];
            sa[tid] += sa[tid + off];
        }
        __syncthreads();
    }
    if (tid == 0) {
        out3[0] = (float)(sl[0] / (double)(T * B));
        out3[1] = (float)(sa[0] / (double)B);
        out3[2] = (float)(sm_[0] / (double)(T * B));
    }
}

// ---------------------------------------------------------------------------
extern "C" void kernel_launch(void* const* d_in, const int* in_sizes, int n_in,
                              void* d_out, int out_size, void* d_ws, size_t ws_size,
                              hipStream_t stream)
{
    const int*   input_seq  = (const int*)d_in[0];
    const int*   input_len  = (const int*)d_in[1];
    const int*   target_seq = (const int*)d_in[2];
    const float* enc_embed  = (const float*)d_in[3];
    const float* enc_Wih    = (const float*)d_in[4];
    const float* enc_Whh    = (const float*)d_in[5];
    const float* enc_bih    = (const float*)d_in[6];
    const float* enc_bhh    = (const float*)d_in[7];
    const float* att_W      = (const float*)d_in[8];
    const float* att_b      = (const float*)d_in[9];
    const float* dec_embed  = (const float*)d_in[10];
    const float* dec_Wih    = (const float*)d_in[11];
    const float* dec_Whh    = (const float*)d_in[12];
    const float* dec_bih    = (const float*)d_in[13];
    const float* dec_bhh    = (const float*)d_in[14];
    const float* mlp_W      = (const float*)d_in[15];
    const float* mlp_b      = (const float*)d_in[16];
    const float* out_W      = (const float*)d_in[17];
    const float* out_b      = (const float*)d_in[18];

    float* out = (float*)d_out;   // [inference (T*B) | loss | acc | all_acc]

    float* gi_tab  = (float*)d_ws;                   // (V, 3H)
    float* mlp_tab = gi_tab + (size_t)VOC * G3;      // (V, H)
    float* h0      = mlp_tab + (size_t)VOC * Hh;     // (B, H)
    float* h1      = h0 + (size_t)B * Hh;
    float* xb      = h1 + (size_t)B * Hh;
    float* nllb    = xb + (size_t)B * Hh;            // (T, B)
    float* enc_out = nllb + (size_t)T * B;           // (S, B, H) ~105 MB

    hipMemsetAsync(h0, 0, (size_t)B * Hh * sizeof(float), stream);

    // Precompute tables
    gemm_at<<<dim3(48, 16), 256, 0, stream>>>(
        enc_embed, enc_Wih, 512, 0, enc_bih, gi_tab, G3);
    gemm_at<<<dim3(16, 16), 256, 0, stream>>>(
        dec_embed, mlp_W, 1024, 0, mlp_b, mlp_tab, Hh);

    // Encoder scan (final h lands in h0: s=199 odd writes h0)
    for (int s = 0; s < S; ++s) {
        const float* hc = (s & 1) ? h1 : h0;
        float* hx = (s & 1) ? h0 : h1;
        enc_step<<<dim3(32, 8), 512, 0, stream>>>(
            hc, hx, gi_tab, input_seq, input_len, enc_Whh, enc_bhh, s, enc_out);
    }

    // Decoder scan: t = 0..T; attn_ls fuses attention+x | logits+softmax(t-1)
    for (int t = 0; t <= T; ++t) {
        const float* hc = (t & 1) ? h1 : h0;
        float* hx = (t & 1) ? h0 : h1;
        attn_ls<<<dim3(2 * B), 256, 0, stream>>>(
            enc_out, hc, att_W, att_b, out_W, out_b, mlp_W, mlp_tab,
            input_len, target_seq, t, xb, nllb, out);
        if (t < T) {
            dec_gru<<<dim3(32, 16), 256, 0, stream>>>(
                xb, hc, dec_Wih, dec_Whh, dec_bih, dec_bhh, hx);
        }
    }

    finalize_k<<<dim3(1), 256, 0, stream>>>(nllb, out, target_seq, out + (size_t)T * B);
}